// Round 14
// baseline (493.531 us; speedup 1.0000x reference)
//
#include <hip/hip_runtime.h>
#include <math.h>

#define BATCH 8
#define NPTS 4096
#define CHAN 128
#define KNN 16
#define EPC 24                 // slow-path survivor buffer capacity
#define MARGIN 0.02f           // >> max |d2_ref - d2_true| (~1e-4); exactness margin

typedef unsigned long long u64;

// Monotone key: ascending u64 == (d2 ascending, idx ascending).
// Ties in d2 break toward lower index == lax.top_k stable order.
__device__ __forceinline__ u64 pack_key(float d2, int idx) {
  unsigned b = __float_as_uint(d2);
  b ^= (unsigned)((int)b >> 31) | 0x80000000u;  // order-preserving fp32 map
  return ((u64)b << 32) | (unsigned)idx;
}

// Inverse of the d2 map (high 32 bits of key -> float d2).
__device__ __forceinline__ float key_d2(u64 k) {
  unsigned m = (unsigned)(k >> 32);
  unsigned b = (m & 0x80000000u) ? (m ^ 0x80000000u) : ~m;
  return __int_as_float((int)b);
}

// Reference d2: inner = ((x0*y0 + x1*y1) + x2*y2) fp32 no-fma (numpy einsum
// order); d2 = (sq_n + sq_m) - 2*inner. Bit-exact vs JAX reference.
__device__ __forceinline__ float d2_ref(float4 q, float ppx, float ppy,
                                        float ppz, float psq) {
  float inner = __fadd_rn(__fadd_rn(__fmul_rn(ppx, q.x), __fmul_rn(ppy, q.y)),
                          __fmul_rn(ppz, q.z));
  return __fsub_rn(__fadd_rn(psq, q.w), __fmul_rn(2.0f, inner));
}

// ----- u64 compare-exchange machinery ---------------------------------------
__device__ __forceinline__ void ce_asc(u64& x, u64& y) {
  bool sw = y < x;
  u64 lo = sw ? y : x;
  u64 hi = sw ? x : y;
  x = lo;
  y = hi;
}

// Batcher merge-exchange sort of 16 u64 keys, ascending. 63 CE.
__device__ __forceinline__ void batcher_sort16_u64(u64 a[16]) {
#define CE(i, j) ce_asc(a[i], a[j])
  CE(0, 8); CE(1, 9); CE(2, 10); CE(3, 11);
  CE(4, 12); CE(5, 13); CE(6, 14); CE(7, 15);
  CE(0, 4); CE(1, 5); CE(2, 6); CE(3, 7);
  CE(8, 12); CE(9, 13); CE(10, 14); CE(11, 15);
  CE(4, 8); CE(5, 9); CE(6, 10); CE(7, 11);
  CE(0, 2); CE(1, 3); CE(4, 6); CE(5, 7);
  CE(8, 10); CE(9, 11); CE(12, 14); CE(13, 15);
  CE(2, 8); CE(3, 9); CE(6, 12); CE(7, 13);
  CE(2, 4); CE(3, 5); CE(6, 8); CE(7, 9); CE(10, 12); CE(11, 13);
  CE(0, 1); CE(2, 3); CE(4, 5); CE(6, 7);
  CE(8, 9); CE(10, 11); CE(12, 13); CE(14, 15);
  CE(1, 8); CE(3, 10); CE(5, 12); CE(7, 14);
  CE(1, 4); CE(3, 6); CE(5, 8); CE(7, 10); CE(9, 12); CE(11, 14);
  CE(1, 2); CE(3, 4); CE(5, 6); CE(7, 8); CE(9, 10); CE(11, 12); CE(13, 14);
#undef CE
}

// Bitonic sort of 32 u64 keys, ascending. 240 CE (slow path only).
__device__ __forceinline__ void bitonic_sort32(u64 a[32]) {
#pragma unroll
  for (int k = 2; k <= 32; k <<= 1) {
#pragma unroll
    for (int j = k >> 1; j > 0; j >>= 1) {
#pragma unroll
      for (int i = 0; i < 32; ++i) {
        int l = i ^ j;
        if (l > i) {
          if ((i & k) == 0) ce_asc(a[i], a[l]);
          else              ce_asc(a[l], a[i]);
        }
      }
    }
  }
}

// T, A both sorted ascending. T <- lowest-16 of (T ∪ A), sorted ascending.
__device__ __forceinline__ void merge_keep16(u64 T[16], const u64 A[16]) {
  u64 nt[16];
#pragma unroll
  for (int i = 0; i < 16; ++i) {
    u64 a = A[15 - i];
    nt[i] = (a < T[i]) ? a : T[i];
  }
#pragma unroll
  for (int j = 8; j > 0; j >>= 1) {
#pragma unroll
    for (int i = 0; i < 16; ++i) {
      int l = i ^ j;
      if (l > i) ce_asc(nt[i], nt[l]);
    }
  }
#pragma unroll
  for (int i = 0; i < 16; ++i) T[i] = nt[i];
}

// ----- i32 packed-key machinery (hot phase 1) ------------------------------
// Packed key = (d2bits & ~255) | seg_local_idx (8-bit). Signed-i32 ascending
// == (trunc(d2), idx) ascending for all d2 >= 0 (negatives sort below all
// positives -> always selected -> exact epilogue fixes internal order).
__device__ __forceinline__ void ce_i32(int& x, int& y) {
  int lo = min(x, y);
  int hi = max(x, y);
  x = lo;
  y = hi;
}

// Batcher merge-exchange sort of 16 i32 keys, ascending. 63 CE.
__device__ __forceinline__ void batcher_sort16_i32(int a[16]) {
#define CE(i, j) ce_i32(a[i], a[j])
  CE(0, 8); CE(1, 9); CE(2, 10); CE(3, 11);
  CE(4, 12); CE(5, 13); CE(6, 14); CE(7, 15);
  CE(0, 4); CE(1, 5); CE(2, 6); CE(3, 7);
  CE(8, 12); CE(9, 13); CE(10, 14); CE(11, 15);
  CE(4, 8); CE(5, 9); CE(6, 10); CE(7, 11);
  CE(0, 2); CE(1, 3); CE(4, 6); CE(5, 7);
  CE(8, 10); CE(9, 11); CE(12, 14); CE(13, 15);
  CE(2, 8); CE(3, 9); CE(6, 12); CE(7, 13);
  CE(2, 4); CE(3, 5); CE(6, 8); CE(7, 9); CE(10, 12); CE(11, 13);
  CE(0, 1); CE(2, 3); CE(4, 5); CE(6, 7);
  CE(8, 9); CE(10, 11); CE(12, 13); CE(14, 15);
  CE(1, 8); CE(3, 10); CE(5, 12); CE(7, 14);
  CE(1, 4); CE(3, 6); CE(5, 8); CE(7, 10); CE(9, 12); CE(11, 14);
  CE(1, 2); CE(3, 4); CE(5, 6); CE(7, 8); CE(9, 10); CE(11, 12); CE(13, 14);
#undef CE
}

// T, A sorted ascending (i32). T <- lowest-16 of (T ∪ A). 80 VALU.
__device__ __forceinline__ void merge_keep16_i32(int T[16], const int A[16]) {
  int nt[16];
#pragma unroll
  for (int i = 0; i < 16; ++i) nt[i] = min(A[15 - i], T[i]);
#pragma unroll
  for (int j = 8; j > 0; j >>= 1) {
#pragma unroll
    for (int i = 0; i < 16; ++i) {
      int l = i ^ j;
      if (l > i) ce_i32(nt[i], nt[l]);
    }
  }
#pragma unroll
  for (int i = 0; i < 16; ++i) T[i] = nt[i];
}

// ---------------------------------------------------------------------------
// Kernel 0: pack x (B,3,N planar) -> packed[b][m] = (x, y, z, sq) float4.
// sq uses the exact rounding chain of the reference -> downstream bit-exact.
// ---------------------------------------------------------------------------
__global__ __launch_bounds__(256) void pack_kernel(
    const float* __restrict__ x, float4* __restrict__ packed) {
  int t = blockIdx.x * 256 + threadIdx.x;  // over BATCH*NPTS
  int b = t / NPTS;
  int m = t % NPTS;
  const float* xb = x + (size_t)b * 3 * NPTS;
  float px = xb[m];
  float py = xb[NPTS + m];
  float pz = xb[2 * NPTS + m];
  float sq = __fadd_rn(__fadd_rn(__fmul_rn(px, px), __fmul_rn(py, py)),
                       __fmul_rn(pz, pz));
  packed[t] = make_float4(px, py, pz, sq);
}

// ---------------------------------------------------------------------------
// Kernel 0b: counting-rank by (x, idx) ascending -> scatter packed into
// x-sorted order. spacked[b][rank] = packed[b][n], soidx[b][rank] = n.
// Bijective (total order) -> collision-free scatter. ~134M cmps, ~10us.
// ---------------------------------------------------------------------------
__global__ __launch_bounds__(256) void xsort_kernel(
    const float* __restrict__ x, const float4* __restrict__ packed,
    float4* __restrict__ spacked, int* __restrict__ soidx) {
  const int tile = blockIdx.x % (NPTS / 256);
  const int b = blockIdx.x / (NPTS / 256);
  __shared__ float4 xv[NPTS / 4];  // 16 KB (x-plane of the batch)
  const float* xb = x + (size_t)b * 3 * NPTS;
  const float4* xb4 = reinterpret_cast<const float4*>(xb);
  for (int i = threadIdx.x; i < NPTS / 4; i += 256) xv[i] = xb4[i];
  const int n = tile * 256 + threadIdx.x;
  const float xn = xb[n];
  __syncthreads();
  int c = 0;
#pragma unroll 4
  for (int v = 0; v < NPTS / 4; ++v) {
    float4 f = xv[v];
    int gm = 4 * v;
    c += (f.x < xn) || (f.x == xn && gm < n);
    c += (f.y < xn) || (f.y == xn && gm + 1 < n);
    c += (f.z < xn) || (f.z == xn && gm + 2 < n);
    c += (f.w < xn) || (f.w == xn && gm + 3 < n);
  }
  spacked[(size_t)b * NPTS + c] = packed[(size_t)b * NPTS + n];
  soidx[(size_t)b * NPTS + c] = n;
}

// ---------------------------------------------------------------------------
// scan_segment: lane (point, quadrant q) processes its 4 strided batches of
// the segment [segLo, segLo+segLen) (bases q*16 + k*64 < segLen), producing
// K[16] = exact sorted u64 top-16 (keys carry ORIGINAL indices via soidx) of
// the lane's scanned subset. Proven machinery: 8-bit packed i32 phase-1 +
// r17 guard + fast-rebuild / slow-rescan epilogue (per-lane-subset validity:
// r17 = exact 17th of the lane's scanned set, identical proof as before).
// Lanes with zero batches (tiny partial segments) degrade safely: sentinel
// tau == r17-trunc forces slow path, cnt=0, K = all-sentinel (~0ull) -> no-op
// under merge_keep16.
// ---------------------------------------------------------------------------
__device__ __forceinline__ void scan_segment(
    const float4* __restrict__ sp4, const int* __restrict__ sid, int segLo,
    int segLen, int q, float ppx, float ppy, float ppz, float psq,
    unsigned char* myb, u64 K[16]) {
  int T[16];
#pragma unroll
  for (int i = 0; i < 16; ++i) T[i] = 0x7FFFFFFF;  // sentinel > any real key
  int r17 = 0x7FFFFFFF;

#pragma unroll 1
  for (int k = 0; k < 4; ++k) {
    int base = q * 16 + k * 64;
    if (base >= segLen) continue;
    int A[16];
#pragma unroll
    for (int t = 0; t < 16; ++t) {
      float4 qq = sp4[segLo + base + t];
      int bits = __float_as_int(d2_ref(qq, ppx, ppy, ppz, psq));
      A[t] = (bits & 0xFFFFFF00) | (base + t);
    }
    batcher_sort16_i32(A);
    // 17th smallest of (T ∪ A), both sorted: min_i max(T[i], A[15-i])
    int u[16];
#pragma unroll
    for (int i = 0; i < 16; ++i) u[i] = max(T[i], A[15 - i]);
#pragma unroll
    for (int w = 8; w > 0; w >>= 1) {
#pragma unroll
      for (int i = 0; i < 16; ++i) {
        if (i < w) u[i] = min(u[i], u[i + w]);
      }
    }
    r17 = min(r17, u[0]);
    merge_keep16_i32(T, A);
  }

  const int tau = T[15] & 0xFFFFFF00;
  const bool slow = ((r17 & 0xFFFFFF00) == tau);

  if (!slow) {
#pragma unroll
    for (int j = 0; j < 16; ++j) {
      int loc = T[j] & 255;
      float4 qq = sp4[segLo + loc];
      float d2 = d2_ref(qq, ppx, ppy, ppz, psq);
      K[j] = pack_key(d2, sid[segLo + loc]);
    }
    batcher_sort16_u64(K);
  } else {
    int cnt = 0;
#pragma unroll 1
    for (int k = 0; k < 4; ++k) {
      int base = q * 16 + k * 64;
      if (base >= segLen) continue;
#pragma unroll 4
      for (int t = 0; t < 16; ++t) {
        int m = base + t;
        float4 qq = sp4[segLo + m];
        int tb = __float_as_int(d2_ref(qq, ppx, ppy, ppz, psq)) & 0xFFFFFF00;
        if (tb <= tau) {
          myb[cnt < EPC - 1 ? cnt : EPC - 1] = (unsigned char)m;
          ++cnt;
        }
      }
    }
    u64 KK[32];
#pragma unroll
    for (int j = 0; j < EPC; ++j) {
      int loc = min((int)myb[j], segLen - 1);  // clamp garbage past cnt
      float4 qq = sp4[segLo + loc];
      float d2 = d2_ref(qq, ppx, ppy, ppz, psq);
      u64 kk = pack_key(d2, sid[segLo + loc]);
      KK[j] = (j < cnt) ? kk : ~0ull;
    }
#pragma unroll
    for (int j = EPC; j < 32; ++j) KK[j] = ~0ull;
    bitonic_sort32(KK);
#pragma unroll
    for (int j = 0; j < 16; ++j) K[j] = KK[j];
  }
}

// ---------------------------------------------------------------------------
// Kernel 1 (pruned sorted-sweep KNN + score, fused): points x-sorted; wave =
// 16 consecutive sorted points x 4 lanes each. Seed segment of 256 around the
// wave's span, then expand left/right in 256-cand segments while any lane's
// slab test (dx^2 <= bound + MARGIN) demands it.
// Exactness: for m outside [Lp,Rp): |x_m - x_n| >= |x_boundary - x_n| (sorted
// order, true values); true dx^2 <= true d2; |d2_ref - d2_true| <= ~1e-4 and
// MARGIN=0.02 >> that, so the stop condition implies computed d2(m) strictly
// exceeds the point's current computed 16th -> m can never enter the top-16.
// bound = quad-min of per-lane subset-16th = upper bound on the union 16th
// (staleness only widens the scan). Final cross-quad shfl merge (R10-proven)
// yields the exact global top-16 with original indices; score in numpy
// pairwise order (validated round 2). No barriers; LDS = 6 KB scratch.
// grid: BATCH * (NPTS/64) = 512 blocks x 256 thr = 2048 waves.
// ---------------------------------------------------------------------------
__global__ __launch_bounds__(256) void knn_score_kernel(
    const float* __restrict__ x, const float4* __restrict__ spacked,
    const int* __restrict__ soidx, float* __restrict__ score) {
  const int tile = blockIdx.x % (NPTS / 64);
  const int b = blockIdx.x / (NPTS / 64);
  const int lane = threadIdx.x & 63;
  const int wv = threadIdx.x >> 6;
  const int pt = lane >> 2;  // point within wave [0,16)
  const int q = lane & 3;    // quadrant (candidate subset)
  const int wavebase = tile * 64 + wv * 16;
  const int pos = wavebase + pt;  // sorted position of this lane's point
  __shared__ unsigned char scratch[256 * EPC];  // 6 KB slow-path

  const float4* sp4 = spacked + (size_t)b * NPTS;
  const int* sid = soidx + (size_t)b * NPTS;
  float4 sp = sp4[pos];
  const float ppx = sp.x, ppy = sp.y, ppz = sp.z, psq = sp.w;
  const float xn = sp.x;
  unsigned char* myb = scratch + (unsigned)threadIdx.x * EPC;

  int seedLo = wavebase - 112;  // mult of 16; covers wave span +-~100
  if (seedLo < 0) seedLo = 0;
  if (seedLo > NPTS - 256) seedLo = NPTS - 256;

  u64 Kl[16];  // lane's exact top-16 over its scanned subset
  scan_segment(sp4, sid, seedLo, 256, q, ppx, ppy, ppz, psq, myb, Kl);

  float bnd = key_d2(Kl[15]);
  bnd = fminf(bnd, __shfl_xor(bnd, 1));
  bnd = fminf(bnd, __shfl_xor(bnd, 2));  // quad-min: upper bound on union 16th

  int Lp = seedLo, Rp = seedLo + 256;
#pragma unroll 1
  while (true) {
    bool needL = false, needR = false;
    if (Lp > 0) {
      float dx = xn - sp4[Lp - 1].x;  // >= 0 (sorted, Lp-1 < pos)
      needL = (dx * dx <= bnd + MARGIN);
    }
    if (Rp < NPTS) {
      float dx = sp4[Rp].x - xn;  // >= 0
      needR = (dx * dx <= bnd + MARGIN);
    }
    bool doL = __any(needL);
    bool doR = __any(needR);
    if (!doL && !doR) break;
    if (doL) {
      int S = Lp - 256;
      if (S < 0) S = 0;
      u64 Ks[16];
      scan_segment(sp4, sid, S, Lp - S, q, ppx, ppy, ppz, psq, myb, Ks);
      merge_keep16(Kl, Ks);
      Lp = S;
    }
    if (doR) {
      int E = Rp + 256;
      if (E > NPTS) E = NPTS;
      u64 Ks[16];
      scan_segment(sp4, sid, Rp, E - Rp, q, ppx, ppy, ppz, psq, myb, Ks);
      merge_keep16(Kl, Ks);
      Rp = E;
    }
    bnd = key_d2(Kl[15]);
    bnd = fminf(bnd, __shfl_xor(bnd, 1));
    bnd = fminf(bnd, __shfl_xor(bnd, 2));
  }

  // final exact cross-quad merge (all 4 lanes converge to global top-16)
  u64 A[16];
#pragma unroll
  for (int j = 0; j < 16; ++j) A[j] = (u64)__shfl_xor((long long)Kl[j], 1);
  merge_keep16(Kl, A);
#pragma unroll
  for (int j = 0; j < 16; ++j) A[j] = (u64)__shfl_xor((long long)Kl[j], 2);
  merge_keep16(Kl, A);

  // score: lane q in {0,1,2} computes dim q (numpy pairwise), recombine.
  const float* xb = x + (size_t)b * 3 * NPTS;
  const int n_orig = sid[pos];
  float P = 0.0f;
  if (q < 3) {
    const float* xd = xb + (size_t)q * NPTS;
    const float pc = (q == 0) ? ppx : ((q == 1) ? ppy : ppz);
    float r[8];
#pragma unroll
    for (int j = 0; j < 8; ++j) {
      float c0 = xd[(int)(unsigned)Kl[j]];
      float c1 = xd[(int)(unsigned)Kl[j + 8]];
      float e0 = __fsub_rn(c0, pc);
      float e1 = __fsub_rn(c1, pc);
      r[j] = __fadd_rn(__fmul_rn(e0, e0), __fmul_rn(e1, e1));
    }
    float t0 = __fadd_rn(r[0], r[1]);
    float t1 = __fadd_rn(r[2], r[3]);
    float t2 = __fadd_rn(r[4], r[5]);
    float t3 = __fadd_rn(r[6], r[7]);
    P = __fadd_rn(__fadd_rn(t0, t1), __fadd_rn(t2, t3));
  }
  float Pa = __shfl_xor(P, 1);
  float Pb = __shfl_xor(P, 2);
  if (q == 0)
    score[(size_t)b * NPTS + n_orig] = __fadd_rn(__fadd_rn(P, Pa), Pb);
}

// ---------------------------------------------------------------------------
// Kernel 2 (fused rank + scatter, atomics-free; R11-proven): block = 128
// points x 2 scan-halves. rank(n) = #{m: s[m]>s[n] or (s[m]==s[n], m<n)} is
// a total order -> unique c -> collision-free direct scatter == stable desc
// argsort. grid: BATCH*(NPTS/128) = 256 blocks.
// ---------------------------------------------------------------------------
__global__ __launch_bounds__(256) void rank_scatter_kernel(
    const float* __restrict__ score, int* __restrict__ sel, int npts) {
  const int tile = blockIdx.x % (NPTS / 128);
  const int b = blockIdx.x / (NPTS / 128);
  const int p = threadIdx.x & 127;
  const int h = threadIdx.x >> 7;
  __shared__ float4 sv[NPTS / 4];  // 16 KB
  __shared__ int cpart[128];

  const float* sb = score + (size_t)b * NPTS;
  const float4* sb4 = reinterpret_cast<const float4*>(sb);
  for (int i = threadIdx.x; i < NPTS / 4; i += 256) sv[i] = sb4[i];

  const int n = tile * 128 + p;
  const float sn = sb[n];
  __syncthreads();

  int c = 0;
  const int v0 = h * (NPTS / 8);
#pragma unroll 4
  for (int v = v0; v < v0 + NPTS / 8; ++v) {
    float4 f = sv[v];
    int gm = 4 * v;
    c += (f.x > sn) || (f.x == sn && gm < n);
    c += (f.y > sn) || (f.y == sn && gm + 1 < n);
    c += (f.z > sn) || (f.z == sn && gm + 2 < n);
    c += (f.w > sn) || (f.w == sn && gm + 3 < n);
  }
  if (h == 1) cpart[p] = c;
  __syncthreads();
  if (h == 0) {
    c += cpart[p];
    if (c < npts) sel[(size_t)b * npts + c] = n;
  }
}

// ---------------------------------------------------------------------------
// Kernel 3: gather xyz then features into the concatenated flat output.
// ---------------------------------------------------------------------------
__global__ __launch_bounds__(256) void gather_kernel(
    const float* __restrict__ x, const float* __restrict__ y,
    const int* __restrict__ sel, float* __restrict__ out, int npts,
    int total0, int total) {
  int tid = blockIdx.x * blockDim.x + threadIdx.x;
  if (tid >= total) return;
  if (tid < total0) {
    int j = tid % npts;
    int rest = tid / npts;
    int d = rest % 3;
    int b = rest / 3;
    int src = sel[b * npts + j];
    out[tid] = x[((size_t)b * 3 + d) * NPTS + src];
  } else {
    int t = tid - total0;
    int j = t % npts;
    int rest = t / npts;
    int c = rest % CHAN;
    int b = rest / CHAN;
    int src = sel[b * npts + j];
    out[tid] = y[((size_t)b * CHAN + c) * NPTS + src];
  }
}

extern "C" void kernel_launch(void* const* d_in, const int* in_sizes, int n_in,
                              void* d_out, int out_size, void* d_ws,
                              size_t ws_size, hipStream_t stream) {
  const float* x = (const float*)d_in[0];
  const float* y = (const float*)d_in[1];
  float* out = (float*)d_out;

  const int npts = out_size / (BATCH * (3 + CHAN));

  // workspace layout:
  char* w = (char*)d_ws;
  float4* packed = (float4*)w;               // B*N float4 = 2 MB
  w += sizeof(float4) * (size_t)BATCH * NPTS;
  float4* spacked = (float4*)w;              // B*N float4 = 2 MB (x-sorted)
  w += sizeof(float4) * (size_t)BATCH * NPTS;
  int* soidx = (int*)w;                      // B*N i32 (sorted -> original)
  w += sizeof(int) * (size_t)BATCH * NPTS;
  float* score = (float*)w;                  // B*N f32
  w += sizeof(float) * (size_t)BATCH * NPTS;
  int* sel = (int*)w;                        // B*npts i32

  pack_kernel<<<BATCH * NPTS / 256, 256, 0, stream>>>(x, packed);
  xsort_kernel<<<BATCH * (NPTS / 256), 256, 0, stream>>>(x, packed, spacked,
                                                         soidx);
  knn_score_kernel<<<BATCH * (NPTS / 64), 256, 0, stream>>>(x, spacked, soidx,
                                                            score);
  rank_scatter_kernel<<<BATCH * (NPTS / 128), 256, 0, stream>>>(score, sel,
                                                                npts);
  const int total0 = BATCH * 3 * npts;
  gather_kernel<<<(out_size + 255) / 256, 256, 0, stream>>>(
      x, y, sel, out, npts, total0, out_size);
}

// Round 15
// 404.812 us; speedup vs baseline: 1.2192x; 1.2192x over previous
//
#include <hip/hip_runtime.h>
#include <math.h>

#define BATCH 8
#define NPTS 4096
#define CHAN 128
#define KNN 16
#define MARGIN 0.02f  // >> total fp32 error of d2_ref/dx^2 (~1e-4); exactness margin

typedef unsigned long long u64;

// Monotone key: ascending u64 == (d2 ascending, idx ascending).
// Ties in d2 break toward lower ORIGINAL index == lax.top_k stable order.
__device__ __forceinline__ u64 pack_key(float d2, int idx) {
  unsigned b = __float_as_uint(d2);
  b ^= (unsigned)((int)b >> 31) | 0x80000000u;  // order-preserving fp32 map
  return ((u64)b << 32) | (unsigned)idx;
}

// Inverse of the d2 map (high 32 bits of key -> float d2).
__device__ __forceinline__ float key_d2(u64 k) {
  unsigned m = (unsigned)(k >> 32);
  unsigned b = (m & 0x80000000u) ? (m ^ 0x80000000u) : ~m;
  return __int_as_float((int)b);
}

// Reference d2: inner = ((x0*y0 + x1*y1) + x2*y2) fp32 no-fma (numpy einsum
// order); d2 = (sq_n + sq_m) - 2*inner. Bit-exact vs JAX reference.
__device__ __forceinline__ float d2_ref(float4 q, float ppx, float ppy,
                                        float ppz, float psq) {
  float inner = __fadd_rn(__fadd_rn(__fmul_rn(ppx, q.x), __fmul_rn(ppy, q.y)),
                          __fmul_rn(ppz, q.z));
  return __fsub_rn(__fadd_rn(psq, q.w), __fmul_rn(2.0f, inner));
}

// ----- u64 compare-exchange machinery ---------------------------------------
__device__ __forceinline__ void ce_asc(u64& x, u64& y) {
  bool sw = y < x;
  u64 lo = sw ? y : x;
  u64 hi = sw ? x : y;
  x = lo;
  y = hi;
}

// Batcher merge-exchange sort of 16 u64 keys, ascending. 63 CE.
__device__ __forceinline__ void batcher_sort16_u64(u64 a[16]) {
#define CE(i, j) ce_asc(a[i], a[j])
  CE(0, 8); CE(1, 9); CE(2, 10); CE(3, 11);
  CE(4, 12); CE(5, 13); CE(6, 14); CE(7, 15);
  CE(0, 4); CE(1, 5); CE(2, 6); CE(3, 7);
  CE(8, 12); CE(9, 13); CE(10, 14); CE(11, 15);
  CE(4, 8); CE(5, 9); CE(6, 10); CE(7, 11);
  CE(0, 2); CE(1, 3); CE(4, 6); CE(5, 7);
  CE(8, 10); CE(9, 11); CE(12, 14); CE(13, 15);
  CE(2, 8); CE(3, 9); CE(6, 12); CE(7, 13);
  CE(2, 4); CE(3, 5); CE(6, 8); CE(7, 9); CE(10, 12); CE(11, 13);
  CE(0, 1); CE(2, 3); CE(4, 5); CE(6, 7);
  CE(8, 9); CE(10, 11); CE(12, 13); CE(14, 15);
  CE(1, 8); CE(3, 10); CE(5, 12); CE(7, 14);
  CE(1, 4); CE(3, 6); CE(5, 8); CE(7, 10); CE(9, 12); CE(11, 14);
  CE(1, 2); CE(3, 4); CE(5, 6); CE(7, 8); CE(9, 10); CE(11, 12); CE(13, 14);
#undef CE
}

// T, A both sorted ascending. T <- lowest-16 of (T ∪ A), sorted ascending.
__device__ __forceinline__ void merge_keep16(u64 T[16], const u64 A[16]) {
  u64 nt[16];
#pragma unroll
  for (int i = 0; i < 16; ++i) {
    u64 a = A[15 - i];
    nt[i] = (a < T[i]) ? a : T[i];
  }
#pragma unroll
  for (int j = 8; j > 0; j >>= 1) {
#pragma unroll
    for (int i = 0; i < 16; ++i) {
      int l = i ^ j;
      if (l > i) ce_asc(nt[i], nt[l]);
    }
  }
#pragma unroll
  for (int i = 0; i < 16; ++i) T[i] = nt[i];
}

// scan one 16-candidate batch starting at sorted position s0; fold into T.
// Exact keys (full d2 bits + original index) -> no guards, no epilogue.
__device__ __forceinline__ void scan16(const float4* __restrict__ sp4,
                                       const int* __restrict__ sid, int s0,
                                       float ppx, float ppy, float ppz,
                                       float psq, u64 T[16]) {
  u64 A[16];
#pragma unroll
  for (int t = 0; t < 16; ++t) {
    float4 q = sp4[s0 + t];
    float d2 = d2_ref(q, ppx, ppy, ppz, psq);
    A[t] = pack_key(d2, sid[s0 + t]);
  }
  batcher_sort16_u64(A);
  merge_keep16(T, A);
}

// ---------------------------------------------------------------------------
// Kernel 0 (pack + x-sort, fused): counting-rank by (x, idx) ascending ->
// scatter (x,y,z,sq) into x-sorted order + sorted->original index map.
// 4 threads/point (quarter-scans combined via shfl), 64 points/block.
// grid: BATCH*(NPTS/64) = 512 blocks. Bijective scatter (total order).
// ---------------------------------------------------------------------------
__global__ __launch_bounds__(256) void xsort_kernel(
    const float* __restrict__ x, float4* __restrict__ spacked,
    int* __restrict__ soidx) {
  const int tile = blockIdx.x % (NPTS / 64);
  const int b = blockIdx.x / (NPTS / 64);
  const int g = threadIdx.x >> 2;  // point within tile [0,64)
  const int s = threadIdx.x & 3;   // quarter
  __shared__ float4 xv[NPTS / 4];  // 16 KB (x-plane of the batch)

  const float* xb = x + (size_t)b * 3 * NPTS;
  const float4* xb4 = reinterpret_cast<const float4*>(xb);
  for (int i = threadIdx.x; i < NPTS / 4; i += 256) xv[i] = xb4[i];
  const int n = tile * 64 + g;
  const float xn = xb[n];
  __syncthreads();

  int c = 0;
  const int v0 = s * (NPTS / 16);
#pragma unroll 4
  for (int v = v0; v < v0 + NPTS / 16; ++v) {
    float4 f = xv[v];
    int gm = 4 * v;
    c += (f.x < xn) || (f.x == xn && gm < n);
    c += (f.y < xn) || (f.y == xn && gm + 1 < n);
    c += (f.z < xn) || (f.z == xn && gm + 2 < n);
    c += (f.w < xn) || (f.w == xn && gm + 3 < n);
  }
  c += __shfl_xor(c, 1);
  c += __shfl_xor(c, 2);  // full rank on all 4 lanes
  if (s == 0) {
    float px = xn;
    float py = xb[NPTS + n];
    float pz = xb[2 * NPTS + n];
    float sq = __fadd_rn(__fadd_rn(__fmul_rn(px, px), __fmul_rn(py, py)),
                         __fmul_rn(pz, pz));
    spacked[(size_t)b * NPTS + c] = make_float4(px, py, pz, sq);
    soidx[(size_t)b * NPTS + c] = n;
  }
}

// ---------------------------------------------------------------------------
// Kernel 1 (pruned sorted-sweep KNN + score): R14's validated-exact sweep,
// re-amortized. Changes vs R14 (which was 2.3x too slow at VALU 28%/occ 14%):
//   * EXACT u64 keys carried through phase 1 (no trunc/r17/tau/slow-path/
//     epilogue/LDS/barriers at all) -- per-segment fixed costs deleted.
//   * 8 lanes/point (wave = 8 pts x 8 lanes), segment 128 = 1 batch/lane,
//     seed 256 = 2 batches/lane. 4096 waves (2x R14) = 4/SIMD.
// Exactness: merge over exact keys is trivially exact over the scanned set;
// prune: m outside [Lp,Rp) has true dx^2 > bnd + MARGIN where bnd (= 8-lane
// min of exact subset 16ths) >= computed union 16th - eps; MARGIN=0.02 >>
// all fp32 error (~1e-4) -> computed d2(m) strictly exceeds the computed
// union 16th -> m can never enter (validated structure, R14 absmax 0.0).
// grid: BATCH*(NPTS/32) = 1024 blocks x 256 thr.
// ---------------------------------------------------------------------------
__global__ __launch_bounds__(256) void knn_score_kernel(
    const float* __restrict__ x, const float4* __restrict__ spacked,
    const int* __restrict__ soidx, float* __restrict__ score) {
  const int blk = blockIdx.x % (NPTS / 32);
  const int b = blockIdx.x / (NPTS / 32);
  const int lane = threadIdx.x & 63;
  const int wv = threadIdx.x >> 6;
  const int pt = lane >> 3;  // point within wave [0,8)
  const int l8 = lane & 7;   // sub-lane [0,8)
  const int wavebase = blk * 32 + wv * 8;
  const int pos = wavebase + pt;  // sorted position of this lane's point

  const float4* sp4 = spacked + (size_t)b * NPTS;
  const int* sid = soidx + (size_t)b * NPTS;
  float4 pp = sp4[pos];
  const float ppx = pp.x, ppy = pp.y, ppz = pp.z, psq = pp.w;
  const float xn = pp.x;

  u64 T[16];
#pragma unroll
  for (int i = 0; i < 16; ++i) T[i] = ~0ull;  // sentinel > any real key

  // seed: 256 candidates centered on the wave's 8-point span
  int seedLo = (wavebase - 124) & ~15;
  if (seedLo < 0) seedLo = 0;
  if (seedLo > NPTS - 256) seedLo = NPTS - 256;
  scan16(sp4, sid, seedLo + l8 * 16, ppx, ppy, ppz, psq, T);
  scan16(sp4, sid, seedLo + 128 + l8 * 16, ppx, ppy, ppz, psq, T);

  // bnd = per-point upper bound on the union 16th (8-lane min, exact d2)
  float bnd = key_d2(T[15]);
  bnd = fminf(bnd, __shfl_xor(bnd, 1));
  bnd = fminf(bnd, __shfl_xor(bnd, 2));
  bnd = fminf(bnd, __shfl_xor(bnd, 4));

  int Lp = seedLo, Rp = seedLo + 256;
#pragma unroll 1
  for (int it = 0; it < 64; ++it) {
    bool needL = false, needR = false;
    if (Lp > 0) {
      float dx = xn - sp4[Lp - 1].x;  // >= 0 (sorted)
      needL = (dx * dx <= bnd + MARGIN);
    }
    if (Rp < NPTS) {
      float dx = sp4[Rp].x - xn;  // >= 0
      needR = (dx * dx <= bnd + MARGIN);
    }
    bool doL = __any(needL);
    bool doR = __any(needR);
    if (!doL && !doR) break;
    if (doL) {
      int S = Lp - 128;
      if (S < 0) S = 0;
      int len = Lp - S;  // multiple of 16
      if (l8 * 16 < len) scan16(sp4, sid, S + l8 * 16, ppx, ppy, ppz, psq, T);
      Lp = S;
    }
    if (doR) {
      int E = Rp + 128;
      if (E > NPTS) E = NPTS;
      int len = E - Rp;  // multiple of 16
      if (l8 * 16 < len) scan16(sp4, sid, Rp + l8 * 16, ppx, ppy, ppz, psq, T);
      Rp = E;
    }
    bnd = key_d2(T[15]);
    bnd = fminf(bnd, __shfl_xor(bnd, 1));
    bnd = fminf(bnd, __shfl_xor(bnd, 2));
    bnd = fminf(bnd, __shfl_xor(bnd, 4));
  }

  // final cross-lane merge: all 8 lanes converge to the point's exact top-16
  u64 A[16];
#pragma unroll
  for (int j = 0; j < 16; ++j) A[j] = (u64)__shfl_xor((long long)T[j], 1);
  merge_keep16(T, A);
#pragma unroll
  for (int j = 0; j < 16; ++j) A[j] = (u64)__shfl_xor((long long)T[j], 2);
  merge_keep16(T, A);
#pragma unroll
  for (int j = 0; j < 16; ++j) A[j] = (u64)__shfl_xor((long long)T[j], 4);
  merge_keep16(T, A);

  // score: lane l8 in {0,1,2} computes dim l8 (numpy pairwise), recombine.
  const float* xb = x + (size_t)b * 3 * NPTS;
  float P = 0.0f;
  if (l8 < 3) {
    const float* xd = xb + (size_t)l8 * NPTS;
    const float pc = (l8 == 0) ? ppx : ((l8 == 1) ? ppy : ppz);
    float r[8];
#pragma unroll
    for (int j = 0; j < 8; ++j) {
      float c0 = xd[(int)(unsigned)T[j]];
      float c1 = xd[(int)(unsigned)T[j + 8]];
      float e0 = __fsub_rn(c0, pc);
      float e1 = __fsub_rn(c1, pc);
      r[j] = __fadd_rn(__fmul_rn(e0, e0), __fmul_rn(e1, e1));
    }
    float t0 = __fadd_rn(r[0], r[1]);
    float t1 = __fadd_rn(r[2], r[3]);
    float t2 = __fadd_rn(r[4], r[5]);
    float t3 = __fadd_rn(r[6], r[7]);
    P = __fadd_rn(__fadd_rn(t0, t1), __fadd_rn(t2, t3));
  }
  float Pa = __shfl_xor(P, 1);
  float Pb = __shfl_xor(P, 2);
  if (l8 == 0)
    score[(size_t)b * NPTS + sid[pos]] = __fadd_rn(__fadd_rn(P, Pa), Pb);
}

// ---------------------------------------------------------------------------
// Kernel 2 (fused rank + scatter, atomics-free; R11-proven): block = 128
// points x 2 scan-halves. rank(n) = #{m: s[m]>s[n] or (s[m]==s[n], m<n)} is
// a total order -> unique c -> collision-free direct scatter == stable desc
// argsort. grid: BATCH*(NPTS/128) = 256 blocks.
// ---------------------------------------------------------------------------
__global__ __launch_bounds__(256) void rank_scatter_kernel(
    const float* __restrict__ score, int* __restrict__ sel, int npts) {
  const int tile = blockIdx.x % (NPTS / 128);
  const int b = blockIdx.x / (NPTS / 128);
  const int p = threadIdx.x & 127;
  const int h = threadIdx.x >> 7;
  __shared__ float4 sv[NPTS / 4];  // 16 KB
  __shared__ int cpart[128];

  const float* sb = score + (size_t)b * NPTS;
  const float4* sb4 = reinterpret_cast<const float4*>(sb);
  for (int i = threadIdx.x; i < NPTS / 4; i += 256) sv[i] = sb4[i];

  const int n = tile * 128 + p;
  const float sn = sb[n];
  __syncthreads();

  int c = 0;
  const int v0 = h * (NPTS / 8);
#pragma unroll 4
  for (int v = v0; v < v0 + NPTS / 8; ++v) {
    float4 f = sv[v];
    int gm = 4 * v;
    c += (f.x > sn) || (f.x == sn && gm < n);
    c += (f.y > sn) || (f.y == sn && gm + 1 < n);
    c += (f.z > sn) || (f.z == sn && gm + 2 < n);
    c += (f.w > sn) || (f.w == sn && gm + 3 < n);
  }
  if (h == 1) cpart[p] = c;
  __syncthreads();
  if (h == 0) {
    c += cpart[p];
    if (c < npts) sel[(size_t)b * npts + c] = n;
  }
}

// ---------------------------------------------------------------------------
// Kernel 3: gather xyz then features into the concatenated flat output.
// ---------------------------------------------------------------------------
__global__ __launch_bounds__(256) void gather_kernel(
    const float* __restrict__ x, const float* __restrict__ y,
    const int* __restrict__ sel, float* __restrict__ out, int npts,
    int total0, int total) {
  int tid = blockIdx.x * blockDim.x + threadIdx.x;
  if (tid >= total) return;
  if (tid < total0) {
    int j = tid % npts;
    int rest = tid / npts;
    int d = rest % 3;
    int b = rest / 3;
    int src = sel[b * npts + j];
    out[tid] = x[((size_t)b * 3 + d) * NPTS + src];
  } else {
    int t = tid - total0;
    int j = t % npts;
    int rest = t / npts;
    int c = rest % CHAN;
    int b = rest / CHAN;
    int src = sel[b * npts + j];
    out[tid] = y[((size_t)b * CHAN + c) * NPTS + src];
  }
}

extern "C" void kernel_launch(void* const* d_in, const int* in_sizes, int n_in,
                              void* d_out, int out_size, void* d_ws,
                              size_t ws_size, hipStream_t stream) {
  const float* x = (const float*)d_in[0];
  const float* y = (const float*)d_in[1];
  float* out = (float*)d_out;

  const int npts = out_size / (BATCH * (3 + CHAN));

  // workspace layout:
  char* w = (char*)d_ws;
  float4* spacked = (float4*)w;              // B*N float4 = 2 MB (x-sorted)
  w += sizeof(float4) * (size_t)BATCH * NPTS;
  int* soidx = (int*)w;                      // B*N i32 (sorted -> original)
  w += sizeof(int) * (size_t)BATCH * NPTS;
  float* score = (float*)w;                  // B*N f32
  w += sizeof(float) * (size_t)BATCH * NPTS;
  int* sel = (int*)w;                        // B*npts i32

  xsort_kernel<<<BATCH * (NPTS / 64), 256, 0, stream>>>(x, spacked, soidx);
  knn_score_kernel<<<BATCH * (NPTS / 32), 256, 0, stream>>>(x, spacked, soidx,
                                                            score);
  rank_scatter_kernel<<<BATCH * (NPTS / 128), 256, 0, stream>>>(score, sel,
                                                                npts);
  const int total0 = BATCH * 3 * npts;
  gather_kernel<<<(out_size + 255) / 256, 256, 0, stream>>>(
      x, y, sel, out, npts, total0, out_size);
}